// Round 1
// baseline (2664.625 us; speedup 1.0000x reference)
//
#include <hip/hip_runtime.h>
#include <cstdint>
#include <cstddef>

#define BB 16
#define LL 2048
#define CC 512   // H*E
#define TK 7     // int(log(2048)) = 7

// ---------------------------------------------------------------------------
// Phase A: partial[b, tileJ, i] = sum over j in J-tile of
//            P[i,j] = dot(q_row[b,(i+j)%L,:], k_row[b,j,:])
// 64x64 output tile per block, 4x4 per thread, c-chunks of 16 staged in LDS.
// ---------------------------------------------------------------------------
__global__ __launch_bounds__(256) void corr_tiles(const float* __restrict__ q,
                                                  const float* __restrict__ k,
                                                  float* __restrict__ partial) {
  int bid = blockIdx.x;
  const int tileJ = bid & 31; bid >>= 5;
  const int tileI = bid & 31; bid >>= 5;
  const int b = bid;
  const int I = tileI * 64, J = tileJ * 64;
  const int base = (I + J) & (LL - 1);

  __shared__ float Qs[128][17];   // rows base..base+127 (need 0..126)
  __shared__ float Ks[64][17];

  const int tid = threadIdx.x;
  const int tx = tid & 15, ty = tid >> 4;

  float acc[4][4] = {};

  const float* qb = q + (size_t)b * LL * CC;
  const float* kb = k + (size_t)b * LL * CC;

  for (int cb = 0; cb < CC; cb += 16) {
    // Load Q tile: 128 rows x 16 cols = 512 float4, 2 per thread.
    {
      int idx = tid;
#pragma unroll
      for (int it = 0; it < 2; ++it) {
        const int r = idx >> 2, c4 = (idx & 3) * 4;
        const int row = (base + r) & (LL - 1);
        const float4 vv = *reinterpret_cast<const float4*>(qb + (size_t)row * CC + cb + c4);
        Qs[r][c4 + 0] = vv.x; Qs[r][c4 + 1] = vv.y;
        Qs[r][c4 + 2] = vv.z; Qs[r][c4 + 3] = vv.w;
        idx += 256;
      }
      // K tile: 64 rows x 16 cols = 256 float4, 1 per thread.
      const int r = tid >> 2, c4 = (tid & 3) * 4;
      const float4 vv = *reinterpret_cast<const float4*>(kb + (size_t)(J + r) * CC + cb + c4);
      Ks[r][c4 + 0] = vv.x; Ks[r][c4 + 1] = vv.y;
      Ks[r][c4 + 2] = vv.z; Ks[r][c4 + 3] = vv.w;
    }
    __syncthreads();

    const int rbase = (ty + tx) * 4;
#pragma unroll
    for (int c = 0; c < 16; ++c) {
      float kv[4], qv[7];
#pragma unroll
      for (int dj = 0; dj < 4; ++dj) kv[dj] = Ks[tx * 4 + dj][c];
#pragma unroll
      for (int s = 0; s < 7; ++s) qv[s] = Qs[rbase + s][c];
#pragma unroll
      for (int di = 0; di < 4; ++di)
#pragma unroll
        for (int dj = 0; dj < 4; ++dj)
          acc[di][dj] += qv[di + dj] * kv[dj];
    }
    __syncthreads();
  }

  // Row sums: row i = I + ty*4 + di, summed over the 64 j's of this tile.
#pragma unroll
  for (int di = 0; di < 4; ++di) {
    float r = acc[di][0] + acc[di][1] + acc[di][2] + acc[di][3];
    r += __shfl_xor(r, 1, 16);
    r += __shfl_xor(r, 2, 16);
    r += __shfl_xor(r, 4, 16);
    r += __shfl_xor(r, 8, 16);
    if (tx == 0)
      partial[((size_t)(b * 32 + tileJ)) * LL + I + ty * 4 + di] = r;
  }
}

// ---------------------------------------------------------------------------
// Phase A2: mean_value[b,t] = (1/512) * sum_j partial[b,j,t]
// ---------------------------------------------------------------------------
__global__ __launch_bounds__(256) void reduce_mv(const float* __restrict__ partial,
                                                 float* __restrict__ mv) {
  const int g = blockIdx.x * 256 + threadIdx.x;  // 0..32767
  const int b = g >> 11, t = g & (LL - 1);
  float s = 0.f;
#pragma unroll 8
  for (int j = 0; j < 32; ++j) s += partial[((size_t)(b * 32 + j)) * LL + t];
  mv[g] = s * (1.0f / 512.0f);
}

// ---------------------------------------------------------------------------
// Phase B: per-batch top-7 (value-desc, index-asc tie-break like lax.top_k)
// + softmax over the 7 weights.
// ---------------------------------------------------------------------------
__global__ __launch_bounds__(256) void topk_softmax(const float* __restrict__ mv,
                                                    int* __restrict__ delays,
                                                    float* __restrict__ probs) {
  const int b = blockIdx.x;
  __shared__ float vals[LL];
  __shared__ float rv[256];
  __shared__ int ri[256];
  __shared__ float wsel[TK];
  __shared__ int dsel[TK];
  const int tid = threadIdx.x;
  for (int i = tid; i < LL; i += 256) vals[i] = mv[b * LL + i];
  __syncthreads();

  for (int kk = 0; kk < TK; ++kk) {
    float best = -1e30f;
    int bi = LL;
    for (int i = tid; i < LL; i += 256) {
      const float x = vals[i];
      if (x > best) { best = x; bi = i; }
    }
    rv[tid] = best; ri[tid] = bi;
    __syncthreads();
    for (int s = 128; s > 0; s >>= 1) {
      if (tid < s) {
        const float ov = rv[tid + s];
        const int oi = ri[tid + s];
        if (ov > rv[tid] || (ov == rv[tid] && oi < ri[tid])) { rv[tid] = ov; ri[tid] = oi; }
      }
      __syncthreads();
    }
    if (tid == 0) {
      wsel[kk] = rv[0];
      dsel[kk] = ri[0];
      vals[ri[0]] = -1e30f;
    }
    __syncthreads();
  }

  if (tid == 0) {
    const float m = wsel[0];
    float e[TK], ssum = 0.f;
#pragma unroll
    for (int i = 0; i < TK; ++i) { e[i] = expf(wsel[i] - m); ssum += e[i]; }
    const float inv = 1.0f / ssum;
#pragma unroll
    for (int i = 0; i < TK; ++i) {
      probs[b * TK + i] = e[i] * inv;
      delays[b * TK + i] = dsel[i];
    }
  }
}

// ---------------------------------------------------------------------------
// Phase C: out[b,t,:] = sum_k probs[b,k] * v[b,(t+delay[b,k])%L,:]
// One float4 per thread.
// ---------------------------------------------------------------------------
__global__ __launch_bounds__(256) void agg_out(const float* __restrict__ v,
                                               const int* __restrict__ delays,
                                               const float* __restrict__ probs,
                                               float* __restrict__ out) {
  const int g = blockIdx.x * 256 + threadIdx.x;  // float4 index
  const int inrow = g & 127;        // CC/4 = 128
  const int row = g >> 7;           // b*L + t
  const int b = row >> 11;
  const int t = row & (LL - 1);
  float4 acc = make_float4(0.f, 0.f, 0.f, 0.f);
#pragma unroll
  for (int kk = 0; kk < TK; ++kk) {
    const int d = delays[b * TK + kk];
    const float p = probs[b * TK + kk];
    const int src = (t + d) & (LL - 1);
    const float4 x = reinterpret_cast<const float4*>(v)[(size_t)(b * LL + src) * 128 + inrow];
    acc.x += p * x.x; acc.y += p * x.y; acc.z += p * x.z; acc.w += p * x.w;
  }
  reinterpret_cast<float4*>(out)[g] = acc;
}

// ---------------------------------------------------------------------------
extern "C" void kernel_launch(void* const* d_in, const int* in_sizes, int n_in,
                              void* d_out, int out_size, void* d_ws, size_t ws_size,
                              hipStream_t stream) {
  const float* q = (const float*)d_in[0];
  const float* k = (const float*)d_in[1];
  const float* v = (const float*)d_in[2];
  float* out = (float*)d_out;

  char* ws = (char*)d_ws;
  const size_t PART_BYTES = (size_t)BB * 32 * LL * sizeof(float);   // 4 MiB
  const size_t MV_BYTES = (size_t)BB * LL * sizeof(float);          // 128 KiB
  float* partial = (float*)ws;
  float* mv = (float*)(ws + PART_BYTES);
  int* delays = (int*)(ws + PART_BYTES + MV_BYTES);
  float* probs = (float*)(ws + PART_BYTES + MV_BYTES + 512);

  hipLaunchKernelGGL(corr_tiles, dim3(BB * 32 * 32), dim3(256), 0, stream, q, k, partial);
  hipLaunchKernelGGL(reduce_mv, dim3((BB * LL) / 256), dim3(256), 0, stream, partial, mv);
  hipLaunchKernelGGL(topk_softmax, dim3(BB), dim3(256), 0, stream, mv, delays, probs);
  hipLaunchKernelGGL(agg_out, dim3((BB * LL * (CC / 4)) / 256), dim3(256), 0, stream,
                     v, delays, probs, out);
}

// Round 2
// 328.631 us; speedup vs baseline: 8.1083x; 8.1083x over previous
//
#include <hip/hip_runtime.h>
#include <hip/hip_bf16.h>
#include <cstdint>
#include <cstddef>

#define BB 16
#define LL 2048
#define CC 512   // H*E
#define TK 7     // int(log(2048)) = 7

typedef __attribute__((ext_vector_type(8))) short bf16x8;
typedef __attribute__((ext_vector_type(4))) float f32x4;

// ---------------------------------------------------------------------------
// Phase 0: split fp32 -> bf16 hi + bf16 lo  (x = hi + lo to ~2^-17 rel)
// One float4 per thread.
// ---------------------------------------------------------------------------
__global__ __launch_bounds__(256) void split_hl(const float* __restrict__ x,
                                                ushort* __restrict__ hi,
                                                ushort* __restrict__ lo) {
  const size_t g = (size_t)blockIdx.x * 256 + threadIdx.x;
  const float4 v = reinterpret_cast<const float4*>(x)[g];
  const float f[4] = {v.x, v.y, v.z, v.w};
  ushort h[4], l[4];
#pragma unroll
  for (int i = 0; i < 4; ++i) {
    __hip_bfloat16 hb = __float2bfloat16(f[i]);
    h[i] = *reinterpret_cast<const ushort*>(&hb);
    __hip_bfloat16 lb = __float2bfloat16(f[i] - __bfloat162float(hb));
    l[i] = *reinterpret_cast<const ushort*>(&lb);
  }
  reinterpret_cast<ushort4*>(hi)[g] = make_ushort4(h[0], h[1], h[2], h[3]);
  reinterpret_cast<ushort4*>(lo)[g] = make_ushort4(l[0], l[1], l[2], l[3]);
}

// ---------------------------------------------------------------------------
// Phase A: per (b, tI, tJ): 128x128 tile of S = Q*K^T (K-dim C=512) with
// 3-product bf16 split MFMA, then reduce the tile along circular diagonals
// d = u - j + 127 in [0,254] and write 255 partial sums.
// 256 threads = 4 waves (2x2), each wave 64x64 via 4x4 frags of 16x16x32.
// ---------------------------------------------------------------------------
__global__ __launch_bounds__(256, 2) void corr_gemm(const ushort* __restrict__ qh,
                                                    const ushort* __restrict__ ql,
                                                    const ushort* __restrict__ kh,
                                                    const ushort* __restrict__ kl,
                                                    float* __restrict__ partial) {
  int bid = blockIdx.x;
  const int tJ = bid & 15; bid >>= 4;
  const int tI = bid & 15; bid >>= 4;
  const int b = bid;
  const int I = tI * 128, J = tJ * 128;

  // stage: 4 tiles [128 rows][64 k] bf16 = 16 KB each (Ah, Al, Bh, Bl) = 64 KB
  // T: transposed fp32 tile [j 128][u 132-pad] = 66 KB  (union: 66 KB)
  __shared__ __align__(16) union SM {
    ushort stage[4][128 * 64];
    float T[128 * 132];
  } sm;

  const int tid = threadIdx.x;
  const int lane = tid & 63;
  const int wv = tid >> 6;
  const int wr = wv >> 1, wc = wv & 1;   // wave grid 2x2
  const int fr = lane & 15, fq = lane >> 4;

  const size_t bbase = (size_t)b * LL * CC;
  const ushort* src[4] = { qh + bbase + (size_t)I * CC,   // Ah
                           ql + bbase + (size_t)I * CC,   // Al
                           kh + bbase + (size_t)J * CC,   // Bh
                           kl + bbase + (size_t)J * CC }; // Bl

  f32x4 acc[4][4] = {};

  const int wave_slot = (tid & ~63);

  for (int cb = 0; cb < CC; cb += 64) {
    // ---- stage 4 tiles via global_load_lds (16 B/lane, linear LDS) ----
#pragma unroll
    for (int t = 0; t < 4; ++t) {
#pragma unroll
      for (int r = 0; r < 4; ++r) {
        const int n = r * 256 + tid;             // 0..1023 16B-chunks
        const int row = n >> 3, c16 = n & 7;     // 64 ushort/row = 8 chunks
        const ushort* g = src[t] + (size_t)row * CC + cb + c16 * 8;
        char* lp = (char*)sm.stage[t] + (r * 256 + wave_slot) * 16;
        __builtin_amdgcn_global_load_lds(
            (const __attribute__((address_space(1))) void*)g,
            (__attribute__((address_space(3))) void*)lp, 16, 0, 0);
      }
    }
    __syncthreads();

    // ---- compute: 2 sub-K steps of 32 ----
#pragma unroll
    for (int kk = 0; kk < 64; kk += 32) {
      bf16x8 a0[4], b0[4], b1[4], a1[4];
#pragma unroll
      for (int m = 0; m < 4; ++m)
        a0[m] = *reinterpret_cast<const bf16x8*>(
            &sm.stage[0][(wr * 64 + m * 16 + fr) * 64 + kk + fq * 8]);
#pragma unroll
      for (int n = 0; n < 4; ++n)
        b0[n] = *reinterpret_cast<const bf16x8*>(
            &sm.stage[2][(wc * 64 + n * 16 + fr) * 64 + kk + fq * 8]);
#pragma unroll
      for (int m = 0; m < 4; ++m)
#pragma unroll
        for (int n = 0; n < 4; ++n)
          acc[m][n] = __builtin_amdgcn_mfma_f32_16x16x32_bf16(a0[m], b0[n], acc[m][n], 0, 0, 0);
#pragma unroll
      for (int n = 0; n < 4; ++n)
        b1[n] = *reinterpret_cast<const bf16x8*>(
            &sm.stage[3][(wc * 64 + n * 16 + fr) * 64 + kk + fq * 8]);
#pragma unroll
      for (int m = 0; m < 4; ++m)
#pragma unroll
        for (int n = 0; n < 4; ++n)
          acc[m][n] = __builtin_amdgcn_mfma_f32_16x16x32_bf16(a0[m], b1[n], acc[m][n], 0, 0, 0);
#pragma unroll
      for (int m = 0; m < 4; ++m)
        a1[m] = *reinterpret_cast<const bf16x8*>(
            &sm.stage[1][(wr * 64 + m * 16 + fr) * 64 + kk + fq * 8]);
#pragma unroll
      for (int m = 0; m < 4; ++m)
#pragma unroll
        for (int n = 0; n < 4; ++n)
          acc[m][n] = __builtin_amdgcn_mfma_f32_16x16x32_bf16(a1[m], b0[n], acc[m][n], 0, 0, 0);
    }
    __syncthreads();
  }

  // ---- epilogue: write tile transposed T[j][u], reduce diagonals ----
  // C/D layout: col = lane&15 (j), row = fq*4 + reg (u)
#pragma unroll
  for (int m = 0; m < 4; ++m)
#pragma unroll
    for (int n = 0; n < 4; ++n) {
      const int jl = wc * 64 + n * 16 + fr;
      const int u0 = wr * 64 + m * 16 + fq * 4;
      *reinterpret_cast<f32x4*>(&sm.T[jl * 132 + u0]) = acc[m][n];
    }
  __syncthreads();

  if (tid < 255) {
    const int d = tid - 127;  // u - j
    const int jlo = (d < 0) ? -d : 0;
    const int jhi = (d > 0) ? 128 - d : 128;
    float s = 0.f;
    for (int j = jlo; j < jhi; ++j) s += sm.T[j * 132 + j + d];
    partial[(((size_t)b * 16 + tI) * 16 + tJ) * 256 + tid] = s;
  }
}

// ---------------------------------------------------------------------------
// Phase A2: mv[b,i] = (1/512) * sum over tiles of matching diagonal slot.
// Global diag i = (I - J + d - 127) mod L  ->  d = (i - 128(tI-tJ) + 127) mod L
// ---------------------------------------------------------------------------
__global__ __launch_bounds__(256) void reduce_mv(const float* __restrict__ partial,
                                                 float* __restrict__ mv) {
  const int g = blockIdx.x * 256 + threadIdx.x;  // 0..32767
  const int b = g >> 11, i = g & (LL - 1);
  float s = 0.f;
  for (int tI = 0; tI < 16; ++tI)
#pragma unroll
    for (int tJ = 0; tJ < 16; ++tJ) {
      const int d = (i - ((tI - tJ) << 7) + 127 + 4096) & (LL - 1);
      if (d < 255) s += partial[(((size_t)b * 16 + tI) * 16 + tJ) * 256 + d];
    }
  mv[g] = s * (1.0f / 512.0f);
}

// ---------------------------------------------------------------------------
// Phase B: per-batch top-7 (value-desc, index-asc tie-break) + softmax.
// ---------------------------------------------------------------------------
__global__ __launch_bounds__(256) void topk_softmax(const float* __restrict__ mv,
                                                    int* __restrict__ delays,
                                                    float* __restrict__ probs) {
  const int b = blockIdx.x;
  __shared__ float vals[LL];
  __shared__ float rv[256];
  __shared__ int ri[256];
  __shared__ float wsel[TK];
  __shared__ int dsel[TK];
  const int tid = threadIdx.x;
  for (int i = tid; i < LL; i += 256) vals[i] = mv[b * LL + i];
  __syncthreads();

  for (int kk = 0; kk < TK; ++kk) {
    float best = -1e30f;
    int bi = LL;
    for (int i = tid; i < LL; i += 256) {
      const float x = vals[i];
      if (x > best) { best = x; bi = i; }
    }
    rv[tid] = best; ri[tid] = bi;
    __syncthreads();
    for (int s = 128; s > 0; s >>= 1) {
      if (tid < s) {
        const float ov = rv[tid + s];
        const int oi = ri[tid + s];
        if (ov > rv[tid] || (ov == rv[tid] && oi < ri[tid])) { rv[tid] = ov; ri[tid] = oi; }
      }
      __syncthreads();
    }
    if (tid == 0) {
      wsel[kk] = rv[0];
      dsel[kk] = ri[0];
      vals[ri[0]] = -1e30f;
    }
    __syncthreads();
  }

  if (tid == 0) {
    const float m = wsel[0];
    float e[TK], ssum = 0.f;
#pragma unroll
    for (int i = 0; i < TK; ++i) { e[i] = expf(wsel[i] - m); ssum += e[i]; }
    const float inv = 1.0f / ssum;
#pragma unroll
    for (int i = 0; i < TK; ++i) {
      probs[b * TK + i] = e[i] * inv;
      delays[b * TK + i] = dsel[i];
    }
  }
}

// ---------------------------------------------------------------------------
// Phase C: out[b,t,:] = sum_k probs[b,k] * v[b,(t+delay[b,k])%L,:]
// ---------------------------------------------------------------------------
__global__ __launch_bounds__(256) void agg_out(const float* __restrict__ v,
                                               const int* __restrict__ delays,
                                               const float* __restrict__ probs,
                                               float* __restrict__ out) {
  const int g = blockIdx.x * 256 + threadIdx.x;  // float4 index
  const int inrow = g & 127;        // CC/4 = 128
  const int row = g >> 7;           // b*L + t
  const int b = row >> 11;
  const int t = row & (LL - 1);
  float4 acc = make_float4(0.f, 0.f, 0.f, 0.f);
#pragma unroll
  for (int kk = 0; kk < TK; ++kk) {
    const int d = delays[b * TK + kk];
    const float p = probs[b * TK + kk];
    const int srcr = (t + d) & (LL - 1);
    const float4 x = reinterpret_cast<const float4*>(v)[(size_t)(b * LL + srcr) * 128 + inrow];
    acc.x += p * x.x; acc.y += p * x.y; acc.z += p * x.z; acc.w += p * x.w;
  }
  reinterpret_cast<float4*>(out)[g] = acc;
}

// ---------------------------------------------------------------------------
extern "C" void kernel_launch(void* const* d_in, const int* in_sizes, int n_in,
                              void* d_out, int out_size, void* d_ws, size_t ws_size,
                              hipStream_t stream) {
  const float* q = (const float*)d_in[0];
  const float* k = (const float*)d_in[1];
  const float* v = (const float*)d_in[2];
  float* out = (float*)d_out;

  char* ws = (char*)d_ws;
  const size_t NELEM = (size_t)BB * LL * CC;       // 16.78M
  const size_t HL = NELEM * sizeof(ushort);        // 33.55 MB per array
  ushort* qh = (ushort*)(ws);
  ushort* ql = (ushort*)(ws + HL);
  ushort* kh = (ushort*)(ws + 2 * HL);
  ushort* kl = (ushort*)(ws + 3 * HL);
  float* partial = (float*)(ws + 4 * HL);                       // 4 MB
  const size_t PART = (size_t)BB * 16 * 16 * 256 * sizeof(float);
  float* mv = (float*)(ws + 4 * HL + PART);                     // 128 KB
  int* delays = (int*)(ws + 4 * HL + PART + (size_t)BB * LL * 4);
  float* probs = (float*)(ws + 4 * HL + PART + (size_t)BB * LL * 4 + 512);

  const int nf4blocks = (int)(NELEM / 4 / 256);  // 16384
  hipLaunchKernelGGL(split_hl, dim3(nf4blocks), dim3(256), 0, stream, q, qh, ql);
  hipLaunchKernelGGL(split_hl, dim3(nf4blocks), dim3(256), 0, stream, k, kh, kl);
  hipLaunchKernelGGL(corr_gemm, dim3(BB * 16 * 16), dim3(256), 0, stream, qh, ql, kh, kl, partial);
  hipLaunchKernelGGL(reduce_mv, dim3((BB * LL) / 256), dim3(256), 0, stream, partial, mv);
  hipLaunchKernelGGL(topk_softmax, dim3(BB), dim3(256), 0, stream, mv, delays, probs);
  hipLaunchKernelGGL(agg_out, dim3((int)(NELEM / 4 / 256)), dim3(256), 0, stream,
                     v, delays, probs, out);
}

// Round 3
// 169.271 us; speedup vs baseline: 15.7417x; 1.9414x over previous
//
#include <hip/hip_runtime.h>
#include <cstdint>
#include <cstddef>

#define BB 16
#define LL 2048
#define CC 512   // H*E
#define TK 7     // int(log(2048)) = 7
#define PD(a) ((a) + ((a) >> 5))   // LDS pad: +1 float per 32

typedef float2 cf;

__device__ inline cf cadd(cf a, cf b){ return make_float2(a.x + b.x, a.y + b.y); }
__device__ inline cf csub(cf a, cf b){ return make_float2(a.x - b.x, a.y - b.y); }
__device__ inline cf cmul(cf a, cf b){ return make_float2(a.x*b.x - a.y*b.y, a.x*b.y + a.y*b.x); }

// S*i*z : forward S=-1 -> (z.y, -z.x); inverse S=+1 -> (-z.y, z.x)
template<int S> __device__ inline cf crot(cf z){
  return (S < 0) ? make_float2(z.y, -z.x) : make_float2(-z.y, z.x);
}

template<int S> __device__ inline void dft4(cf* x){
  const cf t0 = cadd(x[0], x[2]), t1 = csub(x[0], x[2]);
  const cf t2 = cadd(x[1], x[3]), t3 = csub(x[1], x[3]);
  const cf r = crot<S>(t3);
  x[0] = cadd(t0, t2); x[2] = csub(t0, t2);
  x[1] = cadd(t1, r);  x[3] = csub(t1, r);
}

template<int S> __device__ inline void dft8(cf* x){
  cf e[4] = { x[0], x[2], x[4], x[6] };
  cf o[4] = { x[1], x[3], x[5], x[7] };
  dft4<S>(e); dft4<S>(o);
  const float H = 0.70710678118654752440f;
  o[1] = cmul(o[1], make_float2(H, (float)S * H));
  o[2] = crot<S>(o[2]);
  o[3] = cmul(o[3], make_float2(-H, (float)S * H));
  x[0] = cadd(e[0], o[0]); x[4] = csub(e[0], o[0]);
  x[1] = cadd(e[1], o[1]); x[5] = csub(e[1], o[1]);
  x[2] = cadd(e[2], o[2]); x[6] = csub(e[2], o[2]);
  x[3] = cadd(e[3], o[3]); x[7] = csub(e[3], o[3]);
}

struct Tw { cf w2[7], w3[7], w4a[3], w4b[3]; };

template<int S>
__device__ inline void make_tw(int tid, Tw& T){
  const float base = (float)S * 6.283185307179586f / 2048.0f;
  const int j7 = tid & 7, j63 = tid & 63;
#pragma unroll
  for (int i = 0; i < 7; ++i){
    float s, c;
    __sincosf(base * (float)(32 * (i + 1) * j7), &s, &c);  T.w2[i] = make_float2(c, s);
    __sincosf(base * (float)( 4 * (i + 1) * j63), &s, &c); T.w3[i] = make_float2(c, s);
  }
#pragma unroll
  for (int i = 0; i < 3; ++i){
    float s, c;
    __sincosf(base * (float)((i + 1) * tid), &s, &c);         T.w4a[i] = make_float2(c, s);
    __sincosf(base * (float)((i + 1) * (tid + 256)), &s, &c); T.w4b[i] = make_float2(c, s);
  }
}

// stage 1 (radix-8, Ls=1, no twiddles): x already loaded from A; write B (padded SoA)
template<int S>
__device__ inline void stage1(cf* x, float* Bre, float* Bim, int tid){
  dft8<S>(x);
  const int base = tid << 3;
#pragma unroll
  for (int t = 0; t < 8; ++t){ const int p = PD(base + t); Bre[p] = x[t].x; Bim[p] = x[t].y; }
}

// stages 2 (B->C), 3 (C->B), 4 (B->C); final result in C
template<int S>
__device__ inline void stages234(float* Bre, float* Bim, float* Cre, float* Cim,
                                 const Tw& T, int tid){
  { // stage 2: radix-8, Ls=8
    cf x[8];
#pragma unroll
    for (int t = 0; t < 8; ++t){ const int p = PD(tid + (t << 8)); x[t] = make_float2(Bre[p], Bim[p]); }
#pragma unroll
    for (int t = 1; t < 8; ++t) x[t] = cmul(x[t], T.w2[t - 1]);
    dft8<S>(x);
    const int base = ((tid >> 3) << 6) + (tid & 7);
#pragma unroll
    for (int t = 0; t < 8; ++t){ const int p = PD(base + (t << 3)); Cre[p] = x[t].x; Cim[p] = x[t].y; }
  }
  __syncthreads();
  { // stage 3: radix-8, Ls=64
    cf x[8];
#pragma unroll
    for (int t = 0; t < 8; ++t){ const int p = PD(tid + (t << 8)); x[t] = make_float2(Cre[p], Cim[p]); }
#pragma unroll
    for (int t = 1; t < 8; ++t) x[t] = cmul(x[t], T.w3[t - 1]);
    dft8<S>(x);
    const int base = ((tid >> 6) << 9) + (tid & 63);
#pragma unroll
    for (int t = 0; t < 8; ++t){ const int p = PD(base + (t << 6)); Bre[p] = x[t].x; Bim[p] = x[t].y; }
  }
  __syncthreads();
  { // stage 4: radix-4, Ls=512 (two butterflies per thread)
#pragma unroll
    for (int h = 0; h < 2; ++h){
      const int j = tid + (h << 8);
      cf x[4];
#pragma unroll
      for (int t = 0; t < 4; ++t){ const int p = PD(j + (t << 9)); x[t] = make_float2(Bre[p], Bim[p]); }
      const cf* w = h ? T.w4b : T.w4a;
#pragma unroll
      for (int t = 1; t < 4; ++t) x[t] = cmul(x[t], w[t - 1]);
      dft4<S>(x);
#pragma unroll
      for (int t = 0; t < 4; ++t){ const int p = PD(j + (t << 9)); Cre[p] = x[t].x; Cim[p] = x[t].y; }
    }
  }
  __syncthreads();
}

// async prefetch of one channel's z (2048 cf = 16 KB) into linear LDS buffer
__device__ inline void prefetch_z(const float2* zc, void* Abase, int tid){
#pragma unroll
  for (int r = 0; r < 4; ++r){
    const int n = (r << 8) + tid;
    const char* g = (const char*)zc + (size_t)n * 16;
    char* lp = (char*)Abase + (size_t)(((r << 8) + (tid & ~63)) * 16);
    __builtin_amdgcn_global_load_lds((const __attribute__((address_space(1))) void*)g,
                                     (__attribute__((address_space(3))) void*)lp, 16, 0, 0);
  }
}

// ---------------------------------------------------------------------------
// Phase 1: z[b][c][t] = q[b][t][c] + i*k[b][t][c]   (64x64 LDS tile transpose)
// ---------------------------------------------------------------------------
__global__ __launch_bounds__(256) void transpose_pack(const float* __restrict__ q,
                                                      const float* __restrict__ k,
                                                      float2* __restrict__ z){
  int bid = blockIdx.x;
  const int tt = bid & 31; bid >>= 5;
  const int ct = bid & 7;  bid >>= 3;
  const int b = bid;
  const int t0 = tt << 6, c0 = ct << 6;
  __shared__ float Tq[64][67], Tk[64][67];
  const int tid = threadIdx.x;
  const size_t inbase = ((size_t)b * LL + t0) * CC + c0;
#pragma unroll
  for (int p2 = 0; p2 < 4; ++p2){
    const int row = (p2 << 4) + (tid >> 4);
    const int c4 = (tid & 15) << 2;
    const float4 a = *reinterpret_cast<const float4*>(q + inbase + (size_t)row * CC + c4);
    const float4 e = *reinterpret_cast<const float4*>(k + inbase + (size_t)row * CC + c4);
    Tq[row][c4 + 0] = a.x; Tq[row][c4 + 1] = a.y; Tq[row][c4 + 2] = a.z; Tq[row][c4 + 3] = a.w;
    Tk[row][c4 + 0] = e.x; Tk[row][c4 + 1] = e.y; Tk[row][c4 + 2] = e.z; Tk[row][c4 + 3] = e.w;
  }
  __syncthreads();
  const size_t outbase = ((size_t)b * CC + c0) * LL + t0;
#pragma unroll
  for (int p = 0; p < 16; ++p){
    const int cr = (p << 2) + (tid >> 6);
    const int tl = tid & 63;
    z[outbase + (size_t)cr * LL + tl] = make_float2(Tq[tl][cr], Tk[tl][cr]);
  }
}

// ---------------------------------------------------------------------------
// Phase 2: per (b, group of 16 channels): forward FFT of z_c = q_c + i*k_c,
// accumulate P[f] += Q_c[f]*conj(K_c[f]) in registers; write P into this
// block's own (already consumed) z slice.
// ---------------------------------------------------------------------------
__global__ __launch_bounds__(256) void fft_fwd(float2* __restrict__ z){
  int bid = blockIdx.x;
  const int g = bid & 31; const int b = bid >> 5;
  const int tid = threadIdx.x;
  __shared__ __align__(16) cf A[2048];
  __shared__ float Bre[2112], Bim[2112], Cre[2112], Cim[2112];
  Tw T; make_tw<-1>(tid, T);
  float2* zg = z + (((size_t)b * CC + (size_t)g * 16) << 11);
  float accRe[8] = {0,0,0,0,0,0,0,0};
  float accIm[8] = {0,0,0,0,0,0,0,0};
  prefetch_z(zg, A, tid);
  for (int ch = 0; ch < 16; ++ch){
    asm volatile("s_waitcnt vmcnt(0)" ::: "memory");
    __syncthreads();                       // A holds z of channel ch
    cf x[8];
#pragma unroll
    for (int t = 0; t < 8; ++t) x[t] = A[tid + (t << 8)];
    __syncthreads();                       // all A reads done -> safe to refill
    if (ch < 15) prefetch_z(zg + ((size_t)(ch + 1) << 11), A, tid);
    stage1<-1>(x, Bre, Bim, tid);
    __syncthreads();
    stages234<-1>(Bre, Bim, Cre, Cim, T, tid);
    // combine: Z in C. A=Z[f], B=conj(Z[N-f]);
    // Re(Q conjK) = 0.5*(Bi*Ar + Br*Ai), Im = 0.25*(|A|^2-|B|^2) with B=(Zre_p,-Zim_p)
#pragma unroll
    for (int r = 0; r < 8; ++r){
      const int f = tid + (r << 8);
      const int p = (2048 - f) & 2047;
      const float Ar = Cre[PD(f)], Ai = Cim[PD(f)];
      const float Pr = Cre[PD(p)], Pi = Cim[PD(p)];
      accRe[r] += 0.5f  * (Pi * Ar + Pr * Ai);
      accIm[r] += 0.25f * (Ar * Ar + Ai * Ai - Pr * Pr - Pi * Pi);
    }
  }
#pragma unroll
  for (int r = 0; r < 8; ++r)
    zg[tid + (r << 8)] = make_float2(accRe[r], accIm[r]);
}

// ---------------------------------------------------------------------------
// Phase 3: per b: sum the 32 partial P's, inverse FFT, scale -> mv;
// fused top-7 (value-desc, index-asc ties) + softmax.
// ---------------------------------------------------------------------------
__global__ __launch_bounds__(256) void fft_inv_topk(const float2* __restrict__ z,
                                                    int* __restrict__ delays,
                                                    float* __restrict__ probs){
  const int b = blockIdx.x;
  const int tid = threadIdx.x;
  __shared__ __align__(16) cf A[2048];
  __shared__ float Bre[2112], Bim[2112], Cre[2112], Cim[2112];
  __shared__ float rv[256]; __shared__ int ri[256];
  __shared__ float wsel[TK]; __shared__ int dsel[TK];
  Tw T; make_tw<1>(tid, T);
#pragma unroll
  for (int r = 0; r < 8; ++r){
    const int f = tid + (r << 8);
    float sr = 0.f, si = 0.f;
    for (int g = 0; g < 32; ++g){
      const float2 v = z[(((size_t)b * CC + (size_t)g * 16) << 11) + f];
      sr += v.x; si += v.y;
    }
    A[f] = make_float2(sr, si);
  }
  __syncthreads();
  cf x[8];
#pragma unroll
  for (int t = 0; t < 8; ++t) x[t] = A[tid + (t << 8)];
  __syncthreads();
  stage1<1>(x, Bre, Bim, tid);
  __syncthreads();
  stages234<1>(Bre, Bim, Cre, Cim, T, tid);
  float* vals = (float*)A;   // A free after stage 1 reads
  const float scale = 1.0f / (2048.0f * 512.0f);
#pragma unroll
  for (int r = 0; r < 8; ++r){
    const int t = tid + (r << 8);
    vals[t] = Cre[PD(t)] * scale;
  }
  __syncthreads();
  for (int kk = 0; kk < TK; ++kk){
    float best = -1e30f; int bi = LL;
    for (int i = tid; i < LL; i += 256){
      const float xv = vals[i];
      if (xv > best){ best = xv; bi = i; }
    }
    rv[tid] = best; ri[tid] = bi;
    __syncthreads();
    for (int s = 128; s > 0; s >>= 1){
      if (tid < s){
        const float ov = rv[tid + s]; const int oi = ri[tid + s];
        if (ov > rv[tid] || (ov == rv[tid] && oi < ri[tid])){ rv[tid] = ov; ri[tid] = oi; }
      }
      __syncthreads();
    }
    if (tid == 0){ wsel[kk] = rv[0]; dsel[kk] = ri[0]; vals[ri[0]] = -1e30f; }
    __syncthreads();
  }
  if (tid == 0){
    const float m = wsel[0];
    float e[TK], ssum = 0.f;
#pragma unroll
    for (int i = 0; i < TK; ++i){ e[i] = expf(wsel[i] - m); ssum += e[i]; }
    const float inv = 1.0f / ssum;
#pragma unroll
    for (int i = 0; i < TK; ++i){
      probs[b * TK + i] = e[i] * inv;
      delays[b * TK + i] = dsel[i];
    }
  }
}

// ---------------------------------------------------------------------------
// Phase 4: out[b,t,:] = sum_k probs[b,k] * v[b,(t+delay[b,k])%L,:]
// ---------------------------------------------------------------------------
__global__ __launch_bounds__(256) void agg_out(const float* __restrict__ v,
                                               const int* __restrict__ delays,
                                               const float* __restrict__ probs,
                                               float* __restrict__ out){
  const int g = blockIdx.x * 256 + threadIdx.x;  // float4 index
  const int inrow = g & 127;        // CC/4 = 128
  const int row = g >> 7;           // b*L + t
  const int b = row >> 11;
  const int t = row & (LL - 1);
  float4 acc = make_float4(0.f, 0.f, 0.f, 0.f);
#pragma unroll
  for (int kk = 0; kk < TK; ++kk){
    const int d = delays[b * TK + kk];
    const float p = probs[b * TK + kk];
    const int srcr = (t + d) & (LL - 1);
    const float4 xv = reinterpret_cast<const float4*>(v)[(size_t)(b * LL + srcr) * 128 + inrow];
    acc.x += p * xv.x; acc.y += p * xv.y; acc.z += p * xv.z; acc.w += p * xv.w;
  }
  reinterpret_cast<float4*>(out)[g] = acc;
}

// ---------------------------------------------------------------------------
extern "C" void kernel_launch(void* const* d_in, const int* in_sizes, int n_in,
                              void* d_out, int out_size, void* d_ws, size_t ws_size,
                              hipStream_t stream){
  const float* q = (const float*)d_in[0];
  const float* k = (const float*)d_in[1];
  const float* v = (const float*)d_in[2];
  float* out = (float*)d_out;

  char* ws = (char*)d_ws;
  const size_t Z_BYTES = (size_t)BB * CC * LL * sizeof(float2);  // 134.2 MB
  float2* zbuf = (float2*)ws;
  int* delays = (int*)(ws + Z_BYTES);
  float* probs = (float*)(ws + Z_BYTES + 1024);

  hipLaunchKernelGGL(transpose_pack, dim3(BB * 32 * 8), dim3(256), 0, stream, q, k, zbuf);
  hipLaunchKernelGGL(fft_fwd, dim3(BB * 32), dim3(256), 0, stream, zbuf);
  hipLaunchKernelGGL(fft_inv_topk, dim3(BB), dim3(256), 0, stream, zbuf, delays, probs);
  hipLaunchKernelGGL(agg_out, dim3((BB * LL * (CC / 4)) / 256), dim3(256), 0, stream,
                     v, delays, probs, out);
}

// Round 4
// 154.931 us; speedup vs baseline: 17.1988x; 1.0926x over previous
//
#include <hip/hip_runtime.h>
#include <hip/hip_fp16.h>
#include <cstdint>
#include <cstddef>

#define BB 16
#define LL 2048
#define CC 512   // H*E
#define TK 7     // int(log(2048)) = 7
#define PD(a) ((a) + ((a) >> 5))   // LDS pad: +1 float per 32

typedef float2 cf;

__device__ inline cf cadd(cf a, cf b){ return make_float2(a.x + b.x, a.y + b.y); }
__device__ inline cf csub(cf a, cf b){ return make_float2(a.x - b.x, a.y - b.y); }
__device__ inline cf cmul(cf a, cf b){ return make_float2(a.x*b.x - a.y*b.y, a.x*b.y + a.y*b.x); }

// S*i*z : forward S=-1 -> (z.y, -z.x); inverse S=+1 -> (-z.y, z.x)
template<int S> __device__ inline cf crot(cf z){
  return (S < 0) ? make_float2(z.y, -z.x) : make_float2(-z.y, z.x);
}

template<int S> __device__ inline void dft4(cf* x){
  const cf t0 = cadd(x[0], x[2]), t1 = csub(x[0], x[2]);
  const cf t2 = cadd(x[1], x[3]), t3 = csub(x[1], x[3]);
  const cf r = crot<S>(t3);
  x[0] = cadd(t0, t2); x[2] = csub(t0, t2);
  x[1] = cadd(t1, r);  x[3] = csub(t1, r);
}

template<int S> __device__ inline void dft8(cf* x){
  cf e[4] = { x[0], x[2], x[4], x[6] };
  cf o[4] = { x[1], x[3], x[5], x[7] };
  dft4<S>(e); dft4<S>(o);
  const float H = 0.70710678118654752440f;
  o[1] = cmul(o[1], make_float2(H, (float)S * H));
  o[2] = crot<S>(o[2]);
  o[3] = cmul(o[3], make_float2(-H, (float)S * H));
  x[0] = cadd(e[0], o[0]); x[4] = csub(e[0], o[0]);
  x[1] = cadd(e[1], o[1]); x[5] = csub(e[1], o[1]);
  x[2] = cadd(e[2], o[2]); x[6] = csub(e[2], o[2]);
  x[3] = cadd(e[3], o[3]); x[7] = csub(e[3], o[3]);
}

struct Tw { cf w2[7], w3[7], w4a[3], w4b[3]; };

template<int S>
__device__ inline void make_tw(int tid, Tw& T){
  const float base = (float)S * 6.283185307179586f / 2048.0f;
  const int j7 = tid & 7, j63 = tid & 63;
#pragma unroll
  for (int i = 0; i < 7; ++i){
    float s, c;
    __sincosf(base * (float)(32 * (i + 1) * j7), &s, &c);  T.w2[i] = make_float2(c, s);
    __sincosf(base * (float)( 4 * (i + 1) * j63), &s, &c); T.w3[i] = make_float2(c, s);
  }
#pragma unroll
  for (int i = 0; i < 3; ++i){
    float s, c;
    __sincosf(base * (float)((i + 1) * tid), &s, &c);         T.w4a[i] = make_float2(c, s);
    __sincosf(base * (float)((i + 1) * (tid + 256)), &s, &c); T.w4b[i] = make_float2(c, s);
  }
}

// stage 1 (radix-8, Ls=1, no twiddles): x already loaded; write B (padded SoA)
template<int S>
__device__ inline void stage1(cf* x, float* Bre, float* Bim, int tid){
  dft8<S>(x);
  const int base = tid << 3;
#pragma unroll
  for (int t = 0; t < 8; ++t){ const int p = PD(base + t); Bre[p] = x[t].x; Bim[p] = x[t].y; }
}

// stages 2 (B->C), 3 (C->B), 4 (B->C); final result in C
template<int S>
__device__ inline void stages234(float* Bre, float* Bim, float* Cre, float* Cim,
                                 const Tw& T, int tid){
  { // stage 2: radix-8, Ls=8
    cf x[8];
#pragma unroll
    for (int t = 0; t < 8; ++t){ const int p = PD(tid + (t << 8)); x[t] = make_float2(Bre[p], Bim[p]); }
#pragma unroll
    for (int t = 1; t < 8; ++t) x[t] = cmul(x[t], T.w2[t - 1]);
    dft8<S>(x);
    const int base = ((tid >> 3) << 6) + (tid & 7);
#pragma unroll
    for (int t = 0; t < 8; ++t){ const int p = PD(base + (t << 3)); Cre[p] = x[t].x; Cim[p] = x[t].y; }
  }
  __syncthreads();
  { // stage 3: radix-8, Ls=64
    cf x[8];
#pragma unroll
    for (int t = 0; t < 8; ++t){ const int p = PD(tid + (t << 8)); x[t] = make_float2(Cre[p], Cim[p]); }
#pragma unroll
    for (int t = 1; t < 8; ++t) x[t] = cmul(x[t], T.w3[t - 1]);
    dft8<S>(x);
    const int base = ((tid >> 6) << 9) + (tid & 63);
#pragma unroll
    for (int t = 0; t < 8; ++t){ const int p = PD(base + (t << 6)); Bre[p] = x[t].x; Bim[p] = x[t].y; }
  }
  __syncthreads();
  { // stage 4: radix-4, Ls=512 (two butterflies per thread)
#pragma unroll
    for (int h = 0; h < 2; ++h){
      const int j = tid + (h << 8);
      cf x[4];
#pragma unroll
      for (int t = 0; t < 4; ++t){ const int p = PD(j + (t << 9)); x[t] = make_float2(Bre[p], Bim[p]); }
      const cf* w = h ? T.w4b : T.w4a;
#pragma unroll
      for (int t = 1; t < 4; ++t) x[t] = cmul(x[t], w[t - 1]);
      dft4<S>(x);
#pragma unroll
      for (int t = 0; t < 4; ++t){ const int p = PD(j + (t << 9)); Cre[p] = x[t].x; Cim[p] = x[t].y; }
    }
  }
  __syncthreads();
}

// async prefetch of one channel's z (2048 half2 = 8 KB) into linear LDS buffer
__device__ inline void prefetch_z(const __half2* zc, void* Abase, int tid){
#pragma unroll
  for (int r = 0; r < 2; ++r){
    const int n = (r << 8) + tid;
    const char* g = (const char*)zc + (size_t)n * 16;
    char* lp = (char*)Abase + (size_t)(((r << 8) + (tid & ~63)) * 16);
    __builtin_amdgcn_global_load_lds((const __attribute__((address_space(1))) void*)g,
                                     (__attribute__((address_space(3))) void*)lp, 16, 0, 0);
  }
}

// ---------------------------------------------------------------------------
// Phase 1: z[b][c][t] = half2(q[b][t][c], k[b][t][c])  (64x64 fp16 LDS tile)
// ---------------------------------------------------------------------------
__global__ __launch_bounds__(256) void transpose_pack(const float* __restrict__ q,
                                                      const float* __restrict__ k,
                                                      __half2* __restrict__ z){
  int bid = blockIdx.x;
  const int tt = bid & 31; bid >>= 5;
  const int ct = bid & 7;  bid >>= 3;
  const int b = bid;
  const int t0 = tt << 6, c0 = ct << 6;
  __shared__ __half2 T[64][69];   // [t][c], pad 69 to break bank strides
  const int tid = threadIdx.x;
  const size_t inbase = ((size_t)b * LL + t0) * CC + c0;
#pragma unroll
  for (int p2 = 0; p2 < 4; ++p2){
    const int row = (p2 << 4) + (tid >> 4);     // t_local
    const int c4 = (tid & 15) << 2;             // c_local base
    const float4 a = *reinterpret_cast<const float4*>(q + inbase + (size_t)row * CC + c4);
    const float4 e = *reinterpret_cast<const float4*>(k + inbase + (size_t)row * CC + c4);
    T[row][c4 + 0] = __floats2half2_rn(a.x, e.x);
    T[row][c4 + 1] = __floats2half2_rn(a.y, e.y);
    T[row][c4 + 2] = __floats2half2_rn(a.z, e.z);
    T[row][c4 + 3] = __floats2half2_rn(a.w, e.w);
  }
  __syncthreads();
  const size_t outbase = ((size_t)b * CC + c0) * LL + (size_t)t0;
#pragma unroll
  for (int it = 0; it < 4; ++it){
    const int idx = (it << 8) + tid;
    const int c = idx >> 4;                 // c_local 0..63
    const int t4 = (idx & 15) << 2;         // t_local base (x4)
    const __half2 u0 = T[t4 + 0][c], u1 = T[t4 + 1][c];
    const __half2 u2 = T[t4 + 2][c], u3 = T[t4 + 3][c];
    uint4 w;
    w.x = *reinterpret_cast<const uint*>(&u0);
    w.y = *reinterpret_cast<const uint*>(&u1);
    w.z = *reinterpret_cast<const uint*>(&u2);
    w.w = *reinterpret_cast<const uint*>(&u3);
    *reinterpret_cast<uint4*>(&z[outbase + (size_t)c * LL + t4]) = w;
  }
}

// ---------------------------------------------------------------------------
// Phase 2: per (b, group of 16 channels): forward FFT of z_c = q_c + i*k_c,
// accumulate P[f] += Q_c[f]*conj(K_c[f]) in registers; write P partial.
// ---------------------------------------------------------------------------
__global__ __launch_bounds__(256) void fft_fwd(const __half2* __restrict__ z,
                                               float2* __restrict__ Ppart){
  int bid = blockIdx.x;
  const int g = bid & 31; const int b = bid >> 5;
  const int tid = threadIdx.x;
  __shared__ __align__(16) __half2 A2[2048];
  __shared__ float Bre[2112], Bim[2112], Cre[2112], Cim[2112];
  Tw T; make_tw<-1>(tid, T);
  const __half2* zg = z + (((size_t)b * CC + (size_t)g * 16) << 11);
  float accRe[8] = {0,0,0,0,0,0,0,0};
  float accIm[8] = {0,0,0,0,0,0,0,0};
  prefetch_z(zg, A2, tid);
  for (int ch = 0; ch < 16; ++ch){
    asm volatile("s_waitcnt vmcnt(0)" ::: "memory");
    __syncthreads();                       // A2 holds z of channel ch
    cf x[8];
#pragma unroll
    for (int t = 0; t < 8; ++t) x[t] = __half22float2(A2[tid + (t << 8)]);
    __syncthreads();                       // all A2 reads done -> safe to refill
    if (ch < 15) prefetch_z(zg + ((size_t)(ch + 1) << 11), A2, tid);
    stage1<-1>(x, Bre, Bim, tid);
    __syncthreads();
    stages234<-1>(Bre, Bim, Cre, Cim, T, tid);
    // combine: Z in C. Re(Q conjK) = 0.5*(Bi*Ar + Br*Ai), Im = 0.25*(|A|^2-|B|^2)
#pragma unroll
    for (int r = 0; r < 8; ++r){
      const int f = tid + (r << 8);
      const int p = (2048 - f) & 2047;
      const float Ar = Cre[PD(f)], Ai = Cim[PD(f)];
      const float Pr = Cre[PD(p)], Pi = Cim[PD(p)];
      accRe[r] += 0.5f  * (Pi * Ar + Pr * Ai);
      accIm[r] += 0.25f * (Ar * Ar + Ai * Ai - Pr * Pr - Pi * Pi);
    }
  }
  float2* pp = Ppart + (((size_t)b * 32 + g) << 11);
#pragma unroll
  for (int r = 0; r < 8; ++r)
    pp[tid + (r << 8)] = make_float2(accRe[r], accIm[r]);
}

// ---------------------------------------------------------------------------
// Phase 2b: P[b,f] = sum_g Ppart[b,g,f]
// ---------------------------------------------------------------------------
__global__ __launch_bounds__(256) void reduce_P(const float2* __restrict__ Ppart,
                                                float2* __restrict__ P){
  const int gid = blockIdx.x * 256 + threadIdx.x;  // 0..32767
  const int b = gid >> 11, f = gid & 2047;
  float sr = 0.f, si = 0.f;
#pragma unroll 8
  for (int g = 0; g < 32; ++g){
    const float2 v = Ppart[(((size_t)b * 32 + g) << 11) + f];
    sr += v.x; si += v.y;
  }
  P[((size_t)b << 11) + f] = make_float2(sr, si);
}

// ---------------------------------------------------------------------------
// Phase 3: per b: inverse FFT of P, scale -> mv; fused top-7 + softmax.
// ---------------------------------------------------------------------------
__global__ __launch_bounds__(256) void fft_inv_topk(const float2* __restrict__ P,
                                                    int* __restrict__ delays,
                                                    float* __restrict__ probs){
  const int b = blockIdx.x;
  const int tid = threadIdx.x;
  __shared__ __align__(16) cf A[2048];
  __shared__ float Bre[2112], Bim[2112], Cre[2112], Cim[2112];
  __shared__ float rv[256]; __shared__ int ri[256];
  __shared__ float wsel[TK]; __shared__ int dsel[TK];
  Tw T; make_tw<1>(tid, T);
#pragma unroll
  for (int r = 0; r < 8; ++r){
    const int f = tid + (r << 8);
    A[f] = P[((size_t)b << 11) + f];
  }
  __syncthreads();
  cf x[8];
#pragma unroll
  for (int t = 0; t < 8; ++t) x[t] = A[tid + (t << 8)];
  __syncthreads();
  stage1<1>(x, Bre, Bim, tid);
  __syncthreads();
  stages234<1>(Bre, Bim, Cre, Cim, T, tid);
  float* vals = (float*)A;   // A free after stage 1 reads
  const float scale = 1.0f / (2048.0f * 512.0f);
#pragma unroll
  for (int r = 0; r < 8; ++r){
    const int t = tid + (r << 8);
    vals[t] = Cre[PD(t)] * scale;
  }
  __syncthreads();
  for (int kk = 0; kk < TK; ++kk){
    float best = -1e30f; int bi = LL;
    for (int i = tid; i < LL; i += 256){
      const float xv = vals[i];
      if (xv > best){ best = xv; bi = i; }
    }
    rv[tid] = best; ri[tid] = bi;
    __syncthreads();
    for (int s = 128; s > 0; s >>= 1){
      if (tid < s){
        const float ov = rv[tid + s]; const int oi = ri[tid + s];
        if (ov > rv[tid] || (ov == rv[tid] && oi < ri[tid])){ rv[tid] = ov; ri[tid] = oi; }
      }
      __syncthreads();
    }
    if (tid == 0){ wsel[kk] = rv[0]; dsel[kk] = ri[0]; vals[ri[0]] = -1e30f; }
    __syncthreads();
  }
  if (tid == 0){
    const float m = wsel[0];
    float e[TK], ssum = 0.f;
#pragma unroll
    for (int i = 0; i < TK; ++i){ e[i] = expf(wsel[i] - m); ssum += e[i]; }
    const float inv = 1.0f / ssum;
#pragma unroll
    for (int i = 0; i < TK; ++i){
      probs[b * TK + i] = e[i] * inv;
      delays[b * TK + i] = dsel[i];
    }
  }
}

// ---------------------------------------------------------------------------
// Phase 4: out[b,t,:] = sum_k probs[b,k] * v[b,(t+delay[b,k])%L,:]
// ---------------------------------------------------------------------------
__global__ __launch_bounds__(256) void agg_out(const float* __restrict__ v,
                                               const int* __restrict__ delays,
                                               const float* __restrict__ probs,
                                               float* __restrict__ out){
  const int g = blockIdx.x * 256 + threadIdx.x;  // float4 index
  const int inrow = g & 127;        // CC/4 = 128
  const int row = g >> 7;           // b*L + t
  const int b = row >> 11;
  const int t = row & (LL - 1);
  float4 acc = make_float4(0.f, 0.f, 0.f, 0.f);
#pragma unroll
  for (int kk = 0; kk < TK; ++kk){
    const int d = delays[b * TK + kk];
    const float p = probs[b * TK + kk];
    const int srcr = (t + d) & (LL - 1);
    const float4 xv = reinterpret_cast<const float4*>(v)[(size_t)(b * LL + srcr) * 128 + inrow];
    acc.x += p * xv.x; acc.y += p * xv.y; acc.z += p * xv.z; acc.w += p * xv.w;
  }
  reinterpret_cast<float4*>(out)[g] = acc;
}

// ---------------------------------------------------------------------------
extern "C" void kernel_launch(void* const* d_in, const int* in_sizes, int n_in,
                              void* d_out, int out_size, void* d_ws, size_t ws_size,
                              hipStream_t stream){
  const float* q = (const float*)d_in[0];
  const float* k = (const float*)d_in[1];
  const float* v = (const float*)d_in[2];
  float* out = (float*)d_out;

  char* ws = (char*)d_ws;
  const size_t Z_BYTES  = (size_t)BB * CC * LL * sizeof(__half2);   // 67.1 MB
  const size_t PP_BYTES = (size_t)BB * 32 * LL * sizeof(float2);    // 8.4 MB
  const size_t P_BYTES  = (size_t)BB * LL * sizeof(float2);         // 256 KB
  __half2* zbuf = (__half2*)ws;
  float2* Ppart = (float2*)(ws + Z_BYTES);
  float2* Pbuf  = (float2*)(ws + Z_BYTES + PP_BYTES);
  int* delays = (int*)(ws + Z_BYTES + PP_BYTES + P_BYTES);
  float* probs = (float*)(ws + Z_BYTES + PP_BYTES + P_BYTES + 1024);

  hipLaunchKernelGGL(transpose_pack, dim3(BB * 32 * 8), dim3(256), 0, stream, q, k, zbuf);
  hipLaunchKernelGGL(fft_fwd, dim3(BB * 32), dim3(256), 0, stream, zbuf, Ppart);
  hipLaunchKernelGGL(reduce_P, dim3((BB * LL) / 256), dim3(256), 0, stream, Ppart, Pbuf);
  hipLaunchKernelGGL(fft_inv_topk, dim3(BB), dim3(256), 0, stream, Pbuf, delays, probs);
  hipLaunchKernelGGL(agg_out, dim3((BB * LL * (CC / 4)) / 256), dim3(256), 0, stream,
                     v, delays, probs, out);
}